// Round 12
// baseline (378.646 us; speedup 1.0000x reference)
//
#include <hip/hip_runtime.h>
#include <hip/hip_bf16.h>
#include <stdint.h>
#include <stddef.h>

typedef __bf16 bf16_t;
typedef __attribute__((ext_vector_type(8))) __bf16 bf16x8;
typedef __attribute__((ext_vector_type(4))) __bf16 bf16x4;
typedef __attribute__((ext_vector_type(4))) float f32x4;
typedef __attribute__((ext_vector_type(4))) int i32x4;

#define M_DIM 32768
#define N_DIM 4096
#define K_DIM 1024
#define NT 32  // K / 32

static __device__ __forceinline__ void gload16(const void* g, void* s) {
  __builtin_amdgcn_global_load_lds(
      (const __attribute__((address_space(1))) void*)g,
      (__attribute__((address_space(3))) void*)s,
      16, 0, 0);
}

// ---------------- x: fp32 [M][K] -> bf16 [M][K] ----------------
__global__ void cvt_x_kernel(const float* __restrict__ x, bf16_t* __restrict__ xb) {
  const long n8 = (long)M_DIM * K_DIM / 8;
  long i = (long)blockIdx.x * blockDim.x + threadIdx.x;
  const long stride = (long)gridDim.x * blockDim.x;
  for (; i < n8; i += stride) {
    const float4* p = (const float4*)(x + i * 8);
    float4 v0 = p[0];
    float4 v1 = p[1];
    bf16x8 o;
    o[0] = (__bf16)v0.x; o[1] = (__bf16)v0.y; o[2] = (__bf16)v0.z; o[3] = (__bf16)v0.w;
    o[4] = (__bf16)v1.x; o[5] = (__bf16)v1.y; o[6] = (__bf16)v1.z; o[7] = (__bf16)v1.w;
    *(bf16x8*)(xb + i * 8) = o;
  }
}

// ---------------- w: int32 [K][N] -> bf16 Wt [N][K] (exact) ----------------
__global__ void cvt_w_kernel(const int* __restrict__ qw, bf16_t* __restrict__ wt) {
  __shared__ bf16_t t[64][72];
  const int bk = blockIdx.x & 15;
  const int bn = blockIdx.x >> 4;
  const int k0 = bk * 64, n0 = bn * 64;
  const int tid = threadIdx.x;
  {
    const int kl = tid >> 2;
    const int nc = (tid & 3) * 16;
    const int* src = qw + (long)(k0 + kl) * N_DIM + n0 + nc;
#pragma unroll
    for (int c = 0; c < 4; ++c) {
      i32x4 v = *(const i32x4*)(src + c * 4);
#pragma unroll
      for (int j = 0; j < 4; ++j)
        t[nc + c * 4 + j][kl] = (bf16_t)(float)v[j];
    }
  }
  __syncthreads();
  {
    const int nl = tid >> 2;
    const int kc = (tid & 3) * 16;
    bf16_t* dst = wt + (long)(n0 + nl) * K_DIM + k0 + kc;
#pragma unroll
    for (int j = 0; j < 16; ++j) dst[j] = t[nl][kc + j];
  }
}

// ---------------- GEMM 128x128, BK=32, 4 waves, 3 bufs, dist-2 prefetch --
// Round-11 structure (swizzle verified: SQ_LDS_BANK_CONFLICT == 0) with the
// prefetch distance extended from 1 tile (~790cy, marginal vs LLC latency
// under load) to 2 tiles (~1600cy): 3 rotating 16KB buffers (48KB LDS ->
// 3 blocks/CU), stage tile t+2 at iter t, wait vmcnt(4) (never 0 in-loop).
// Queue at SYNC of tile t = {t(4), t+1(4)}; vmcnt(4) lands exactly tile t.
// WAR: stage(t+2) overwrites buf((t-1)%3); its readers finished before this
// iter's barrier (lgkm dep-wait before MFMA + s_barrier). Waits precede the
// reads they guard (round-7 lesson).
__global__ __launch_bounds__(256, 3) void gemm128_kernel(
    const bf16_t* __restrict__ A, const bf16_t* __restrict__ Bt,
    const float* __restrict__ scale_p, const float* __restrict__ bias,
    float* __restrict__ C) {
  __shared__ __align__(16) char lds[49152];  // 3 x 16KB

  // XCD ownership (bijective; nwg = 8192): XCD x owns tn {4x..4x+3}; tnl
  // iterates fastest so consecutive blocks share one A-tile; all XCDs sweep
  // the same tm window concurrently (A served via LLC).
  const int xcd = blockIdx.x & 7;
  const int slot = blockIdx.x >> 3;        // 0..1023
  const int tn = (xcd << 2) | (slot & 3);  // 0..31
  const int tm = slot >> 2;                // 0..255

  const int tid = threadIdx.x;
  const int wave = tid >> 6;  // 0..3
  const int lane = tid & 63;
  const int lr = lane & 15;
  const int lg = lane >> 4;
  const int wm = wave >> 1;  // 0..1
  const int wn = wave & 1;   // 0..1

  const long aRow0 = (long)tm * 128;
  const long bRow0 = (long)tn * 128;

  // staging: issue = 4KB = 64 rows x 64B; wave w writes rows w*16..w*16+15.
  // Thread covers row srow = w*16 + lane/4; SOURCE chunk pre-swizzled:
  // LDS slot (row,c) holds global chunk c ^ ((row>>1)&3) (bank-conflict-free
  // for ds_read_b128's 8-lane service groups; verified round 11).
  const int srow = wave * 16 + (lane >> 2);
  const int scol = ((lane & 3) ^ ((lane >> 3) & 3)) * 8;
  const bf16_t* aS = A + (aRow0 + srow) * K_DIM + scol;
  const bf16_t* bS = Bt + (bRow0 + srow) * K_DIM + scol;
  char* sBase = lds + wave * 1024;

  // buf at byte offset bo (0/16384/32768): A at bo, B at bo+8192.
#define STG_A(bo, h, t)                                               \
  gload16(aS + (long)((h) * 64) * K_DIM + (t) * 32,                   \
          sBase + (bo) + (h) * 4096)
#define STG_B(bo, h, t)                                               \
  gload16(bS + (long)((h) * 64) * K_DIM + (t) * 32,                   \
          sBase + (bo) + 8192 + (h) * 4096)

  const int ck = ((lg ^ ((lr >> 1) & 3)) << 4);

#define LDA(m) \
  (*(const bf16x8*)(lds + bb + (wm * 64 + (m) * 16 + lr) * 64 + ck))
#define LDB(n) \
  (*(const bf16x8*)(lds + bb + 8192 + (wn * 64 + (n) * 16 + lr) * 64 + ck))

#define SYNC(N)                                                \
  do {                                                         \
    asm volatile("s_waitcnt vmcnt(" #N ")" ::: "memory");      \
    __builtin_amdgcn_s_barrier();                              \
    __builtin_amdgcn_sched_barrier(0);                         \
  } while (0)

#define COMPUTE()                                                        \
  do {                                                                   \
    _Pragma("unroll") for (int m = 0; m < 4; ++m) afr[m] = LDA(m);       \
    _Pragma("unroll") for (int n = 0; n < 4; ++n) bfr[n] = LDB(n);       \
    __builtin_amdgcn_s_setprio(1);                                       \
    _Pragma("unroll") for (int m = 0; m < 4; ++m)                        \
      _Pragma("unroll") for (int n = 0; n < 4; ++n)                      \
        acc[m][n] = __builtin_amdgcn_mfma_f32_16x16x32_bf16(             \
            afr[m], bfr[n], acc[m][n], 0, 0, 0);                         \
    __builtin_amdgcn_s_setprio(0);                                       \
  } while (0)

  f32x4 acc[4][4] = {};
  bf16x8 afr[4], bfr[4];

  // prologue: stage tiles 0 (buf0) and 1 (buf1)
  STG_A(0, 0, 0);
  STG_A(0, 1, 0);
  STG_B(0, 0, 0);
  STG_B(0, 1, 0);
  STG_A(16384, 0, 1);
  STG_A(16384, 1, 1);
  STG_B(16384, 0, 1);
  STG_B(16384, 1, 1);

  int bb = 0;       // buffer holding tile t
  int sb = 32768;   // buffer for tile t+2
#pragma unroll 1
  for (int t = 0; t < NT - 2; ++t) {
    SYNC(4);  // tile t landed (all waves); {t+1} stays in flight
    STG_A(sb, 0, t + 2);
    STG_A(sb, 1, t + 2);
    STG_B(sb, 0, t + 2);
    STG_B(sb, 1, t + 2);
    COMPUTE();
    // rotate: sb = bb, bb = next(bb)
    sb = bb;
    bb = (bb == 32768) ? 0 : bb + 16384;
  }
  {  // t = NT-2: queue = {NT-2(4), NT-1(4)}
    SYNC(4);
    COMPUTE();
    sb = bb;
    bb = (bb == 32768) ? 0 : bb + 16384;
  }
  {  // t = NT-1: queue = {NT-1(4)}
    SYNC(0);
    COMPUTE();
  }

#undef STG_A
#undef STG_B
#undef LDA
#undef LDB
#undef SYNC
#undef COMPUTE

  // epilogue: C/D layout col = lane&15, row = (lane>>4)*4 + reg (verified)
  const float sc = *scale_p;
  const int col_base = (tn << 7) + wn * 64;
  const int row_base = (tm << 7) + wm * 64 + lg * 4;
#pragma unroll
  for (int n = 0; n < 4; ++n) {
    const int col = col_base + n * 16 + lr;
    const float bv = bias[col];
#pragma unroll
    for (int m = 0; m < 4; ++m) {
      float* cp = C + (long)(row_base + m * 16) * N_DIM + col;
#pragma unroll
      for (int j = 0; j < 4; ++j)
        __builtin_nontemporal_store(acc[m][n][j] * sc + bv, cp + (long)j * N_DIM);
    }
  }
}

// ---------------- fallback (ws too small): reg-staged 128^2 kernel --------
__global__ __launch_bounds__(256, 2) void gemm_fb_kernel(
    const float* __restrict__ Af, const bf16_t* __restrict__ Bt,
    const float* __restrict__ scale_p, const float* __restrict__ bias,
    float* __restrict__ C) {
  __shared__ bf16_t lA[128][64];
  __shared__ bf16_t lB[128][64];
  const int nwg = gridDim.x;
  int wg = blockIdx.x;
  wg = (wg & 7) * (nwg >> 3) + (wg >> 3);
  const int tm = wg & 255;
  const int tn = wg >> 8;
  const int tid = threadIdx.x;
  const int wave = tid >> 6;
  const int lane = tid & 63;
  const int lr = lane & 15;
  const int lg = lane >> 4;
  const int wm = wave >> 1;
  const int wn = wave & 1;
  const long aRow0 = (long)tm * 128;
  const long bRow0 = (long)tn * 128;
  const bf16_t* bSrc = Bt + (bRow0 + (tid >> 3)) * K_DIM + (tid & 7) * 8;
  char* ldsB = (char*)&lB[0][0] + wave * 1024;
  f32x4 acc[4][4] = {};
  for (int k0 = 0; k0 < K_DIM; k0 += 64) {
    __syncthreads();
#pragma unroll
    for (int j = 0; j < 8; ++j) {
      const int e = j * 1024 + tid * 4;
      const int row = e >> 6;
      const int col = e & 63;
      float4 v = *(const float4*)(Af + (aRow0 + row) * K_DIM + k0 + col);
      bf16x4 o;
      o[0] = (__bf16)v.x; o[1] = (__bf16)v.y; o[2] = (__bf16)v.z; o[3] = (__bf16)v.w;
      *(bf16x4*)((char*)&lA[0][0] + (size_t)e * 2) = o;
    }
#pragma unroll
    for (int i = 0; i < 4; ++i)
      gload16(bSrc + (long)i * 32 * K_DIM + k0, ldsB + i * 4096);
    __syncthreads();
#pragma unroll
    for (int kk = 0; kk < 2; ++kk) {
      bf16x8 af[4], bg[4];
#pragma unroll
      for (int m = 0; m < 4; ++m)
        af[m] = *(const bf16x8*)&lA[wm * 64 + m * 16 + lr][kk * 32 + lg * 8];
#pragma unroll
      for (int n = 0; n < 4; ++n)
        bg[n] = *(const bf16x8*)&lB[wn * 64 + n * 16 + lr][kk * 32 + lg * 8];
#pragma unroll
      for (int m = 0; m < 4; ++m)
#pragma unroll
        for (int n = 0; n < 4; ++n)
          acc[m][n] = __builtin_amdgcn_mfma_f32_16x16x32_bf16(af[m], bg[n], acc[m][n], 0, 0, 0);
    }
  }
  const float s = *scale_p;
  const int col0 = (tn << 7) + wn * 64;
  const int row0 = (tm << 7) + wm * 64 + lg * 4;
#pragma unroll
  for (int n = 0; n < 4; ++n) {
    const int col = col0 + n * 16 + lr;
    const float bv = bias[col];
#pragma unroll
    for (int m = 0; m < 4; ++m) {
      float* cp = C + (long)(row0 + m * 16) * N_DIM + col;
#pragma unroll
      for (int j = 0; j < 4; ++j)
        cp[(long)j * N_DIM] = acc[m][n][j] * s + bv;
    }
  }
}

extern "C" void kernel_launch(void* const* d_in, const int* in_sizes, int n_in,
                              void* d_out, int out_size, void* d_ws, size_t ws_size,
                              hipStream_t stream) {
  const float* x = (const float*)d_in[0];
  const int* qw = (const int*)d_in[1];  // harness pushes ints as int32
  const float* scale = (const float*)d_in[2];
  const float* bias = (const float*)d_in[3];
  float* out = (float*)d_out;

  const size_t wt_bytes = (size_t)N_DIM * K_DIM * 2;  // 8 MB
  const size_t xb_bytes = (size_t)M_DIM * K_DIM * 2;  // 64 MB
  bf16_t* wt = (bf16_t*)d_ws;
  bf16_t* xb = (bf16_t*)((char*)d_ws + wt_bytes);
  const bool apre = ws_size >= wt_bytes + xb_bytes;

  cvt_w_kernel<<<dim3((K_DIM / 64) * (N_DIM / 64)), dim3(256), 0, stream>>>(qw, wt);

  if (apre) {
    cvt_x_kernel<<<dim3(2048), dim3(256), 0, stream>>>(x, xb);
    gemm128_kernel<<<dim3((M_DIM / 128) * (N_DIM / 128)), dim3(256), 0, stream>>>(
        xb, wt, scale, bias, out);
  } else {
    gemm_fb_kernel<<<dim3((M_DIM / 128) * (N_DIM / 128)), dim3(256), 0, stream>>>(
        x, wt, scale, bias, out);
  }
}

// Round 13
// 316.262 us; speedup vs baseline: 1.1973x; 1.1973x over previous
//
#include <hip/hip_runtime.h>
#include <hip/hip_bf16.h>
#include <stdint.h>
#include <stddef.h>

typedef __bf16 bf16_t;
typedef __attribute__((ext_vector_type(8))) __bf16 bf16x8;
typedef __attribute__((ext_vector_type(4))) __bf16 bf16x4;
typedef __attribute__((ext_vector_type(4))) float f32x4;
typedef __attribute__((ext_vector_type(4))) int i32x4;

#define M_DIM 32768
#define N_DIM 4096
#define K_DIM 1024
#define NT 16  // K / 64

static __device__ __forceinline__ void gload16(const void* g, void* s) {
  __builtin_amdgcn_global_load_lds(
      (const __attribute__((address_space(1))) void*)g,
      (__attribute__((address_space(3))) void*)s,
      16, 0, 0);
}

// ---------------- x: fp32 [M][K] -> bf16 [M][K] ----------------
__global__ void cvt_x_kernel(const float* __restrict__ x, bf16_t* __restrict__ xb) {
  const long n8 = (long)M_DIM * K_DIM / 8;
  long i = (long)blockIdx.x * blockDim.x + threadIdx.x;
  const long stride = (long)gridDim.x * blockDim.x;
  for (; i < n8; i += stride) {
    const float4* p = (const float4*)(x + i * 8);
    float4 v0 = p[0];
    float4 v1 = p[1];
    bf16x8 o;
    o[0] = (__bf16)v0.x; o[1] = (__bf16)v0.y; o[2] = (__bf16)v0.z; o[3] = (__bf16)v0.w;
    o[4] = (__bf16)v1.x; o[5] = (__bf16)v1.y; o[6] = (__bf16)v1.z; o[7] = (__bf16)v1.w;
    *(bf16x8*)(xb + i * 8) = o;
  }
}

// ---------------- w: int32 [K][N] -> bf16 Wt [N][K] (exact) ----------------
__global__ void cvt_w_kernel(const int* __restrict__ qw, bf16_t* __restrict__ wt) {
  __shared__ bf16_t t[64][72];
  const int bk = blockIdx.x & 15;
  const int bn = blockIdx.x >> 4;
  const int k0 = bk * 64, n0 = bn * 64;
  const int tid = threadIdx.x;
  {
    const int kl = tid >> 2;
    const int nc = (tid & 3) * 16;
    const int* src = qw + (long)(k0 + kl) * N_DIM + n0 + nc;
#pragma unroll
    for (int c = 0; c < 4; ++c) {
      i32x4 v = *(const i32x4*)(src + c * 4);
#pragma unroll
      for (int j = 0; j < 4; ++j)
        t[nc + c * 4 + j][kl] = (bf16_t)(float)v[j];
    }
  }
  __syncthreads();
  {
    const int nl = tid >> 2;
    const int kc = (tid & 3) * 16;
    bf16_t* dst = wt + (long)(n0 + nl) * K_DIM + k0 + kc;
#pragma unroll
    for (int j = 0; j < 16; ++j) dst[j] = t[nl][kc + j];
  }
}

// ---------------- GEMM 128x128, BK=64, 4 waves, 2 blocks/CU --------------
// Round-9 skeleton (best measured: GEMM ~275us) with uniform staging slack.
// CHANGE vs round 9: B's LDS halves split along the n-frag axis (like A's
// m-pair split) instead of the wn axis. Consumption then spreads:
//   P1 needs {Ah0,Bh0}, P2 needs {Bh1}, P3 needs {Ah1}, P4 nothing.
// Stage slots P1:Ah0' P2:Bh0' P3:Bh1' P4:Ah1' give every half >=3 phases of
// slack (round 9's Bh1 had only 2), one half landed per wait.
// Waits: vmcnt(4) at P1/P2/P3, none at P4; tail 4/2/0. Queue verified:
//   P1: {Ah0,Bh0,Bh1,Ah1}=8 -> lands Ah0,Bh0;  (stage Ah0' -> 6)
//   P2: {Bh1,Ah1,Ah0'}=6    -> lands Bh1;      (stage Bh0' -> 6)
//   P3: {Ah1,Ah0',Bh0'}=6   -> lands Ah1;      (stage Bh1' -> 6)
//   P4: no wait; stage Ah1' -> 8 (steady).
// A region h: rows {h*32+[0,32)} u {64+h*32+[0,32)}; slot s = wm*32 +
// (m&1)*16 + lr, region (m>>1). B region h: IDENTICAL structure with wn,n:
// rows {h*32+[0,32)} u {64+h*32+[0,32)}; slot = wn*32 + (n&1)*16 + lr,
// region (n>>1). Swizzle invariant (verified 0-conflict): LDS slot s chunk
// c holds global chunk c ^ (s&7); s&7 == lr&7 for all frags; readers use
// ck = ((kk*4+lg) ^ (lr&7))<<4. WAR: each region's last ds_read retires
// (lgkm before its consuming MFMA) >=3 barriers before its overwrite.
__global__ __launch_bounds__(256, 2) void gemm128_kernel(
    const bf16_t* __restrict__ A, const bf16_t* __restrict__ Bt,
    const float* __restrict__ scale_p, const float* __restrict__ bias,
    float* __restrict__ C) {
  __shared__ __align__(16) char lds[65536];

  // XCD ownership (bijective; nwg = 8192): XCD x owns tn {4x..4x+3}; tnl
  // iterates fastest so consecutive blocks share one A-tile; all XCDs sweep
  // the same tm window concurrently (A served via LLC).
  const int xcd = blockIdx.x & 7;
  const int slot = blockIdx.x >> 3;        // 0..1023
  const int tn = (xcd << 2) | (slot & 3);  // 0..31
  const int tm = slot >> 2;                // 0..255

  const int tid = threadIdx.x;
  const int wave = tid >> 6;  // 0..3
  const int lane = tid & 63;
  const int lr = lane & 15;
  const int lg = lane >> 4;
  const int wm = wave >> 1;  // 0..1
  const int wn = wave & 1;   // 0..1

  const long aRow0 = (long)tm * 128;
  const long bRow0 = (long)tn * 128;

  // staging: issue = 4KB = 32 slots x 128B; thread covers slot s = tid>>3,
  // source col chunk pre-swizzled by s&7 (gload_lds dest stays linear)
  const int s = tid >> 3;
  const int scol = ((tid & 7) ^ (s & 7)) * 8;
  const bf16_t* aS = A + (aRow0 + s) * K_DIM + scol;
  const bf16_t* bS = Bt + (bRow0 + s) * K_DIM + scol;
  char* sBase = lds + wave * 1024;

  // buf b (32KB): A regions at b*32768 + h*8192; B at b*32768+16384 + h*8192
#define STG_A(b, h, t)                                                      \
  do {                                                                      \
    gload16(aS + (long)((h) * 32) * K_DIM + (t) * 64,                       \
            sBase + (b) * 32768 + (h) * 8192);                              \
    gload16(aS + (long)((h) * 32 + 64) * K_DIM + (t) * 64,                  \
            sBase + (b) * 32768 + (h) * 8192 + 4096);                       \
  } while (0)
#define STG_B(b, h, t)                                                      \
  do {                                                                      \
    gload16(bS + (long)((h) * 32) * K_DIM + (t) * 64,                       \
            sBase + (b) * 32768 + 16384 + (h) * 8192);                      \
    gload16(bS + (long)((h) * 32 + 64) * K_DIM + (t) * 64,                  \
            sBase + (b) * 32768 + 16384 + (h) * 8192 + 4096);               \
  } while (0)

  const int ck0 = ((0 + lg) ^ (lr & 7)) << 4;
  const int ck1 = ((4 + lg) ^ (lr & 7)) << 4;

#define LDA(m, kk)                                                           \
  (*(const bf16x8*)(lds + bb + ((m) >> 1) * 8192 +                           \
                    (wm * 32 + ((m) & 1) * 16 + lr) * 128 +                  \
                    ((kk) ? ck1 : ck0)))
#define LDB(n, kk)                                                           \
  (*(const bf16x8*)(lds + bb + 16384 + ((n) >> 1) * 8192 +                   \
                    (wn * 32 + ((n) & 1) * 16 + lr) * 128 +                  \
                    ((kk) ? ck1 : ck0)))

#define SYNC(Nimm)                                           \
  do {                                                       \
    asm volatile("s_waitcnt vmcnt(" #Nimm ")" ::: "memory"); \
    __builtin_amdgcn_s_barrier();                            \
    __builtin_amdgcn_sched_barrier(0);                       \
  } while (0)

  f32x4 acc[4][4] = {};
  bf16x8 bfr[4][2], afr[2][2];

#define MFMA_Q(mbase, nbase)                                                  \
  do {                                                                        \
    __builtin_amdgcn_s_setprio(1);                                            \
    _Pragma("unroll") for (int mm = 0; mm < 2; ++mm)                          \
    _Pragma("unroll") for (int nn = 0; nn < 2; ++nn)                          \
    _Pragma("unroll") for (int kk = 0; kk < 2; ++kk)                          \
      acc[(mbase) + mm][(nbase) + nn] =                                       \
          __builtin_amdgcn_mfma_f32_16x16x32_bf16(                            \
              afr[mm][kk], bfr[(nbase) + nn][kk],                             \
              acc[(mbase) + mm][(nbase) + nn], 0, 0, 0);                      \
    __builtin_amdgcn_s_setprio(0);                                            \
  } while (0)

#define RD_B01()                                                              \
  _Pragma("unroll") for (int n = 0; n < 2; ++n) {                             \
    bfr[n][0] = LDB(n, 0);                                                    \
    bfr[n][1] = LDB(n, 1);                                                    \
  }
#define RD_B23()                                                              \
  _Pragma("unroll") for (int n = 2; n < 4; ++n) {                             \
    bfr[n][0] = LDB(n, 0);                                                    \
    bfr[n][1] = LDB(n, 1);                                                    \
  }
#define RD_A01()                                                              \
  _Pragma("unroll") for (int mm = 0; mm < 2; ++mm) {                          \
    afr[mm][0] = LDA(mm, 0);                                                  \
    afr[mm][1] = LDA(mm, 1);                                                  \
  }
#define RD_A23()                                                              \
  _Pragma("unroll") for (int mm = 0; mm < 2; ++mm) {                          \
    afr[mm][0] = LDA(mm + 2, 0);                                              \
    afr[mm][1] = LDA(mm + 2, 1);                                              \
  }

  // prologue: tile 0 in order Ah0, Bh0, Bh1, Ah1 (8 loads)
  STG_A(0, 0, 0);
  STG_B(0, 0, 0);
  STG_B(0, 1, 0);
  STG_A(0, 1, 0);

#pragma unroll 1
  for (int t = 0; t < NT - 1; ++t) {
    const int b = t & 1;
    const int nb = b ^ 1;
    const int bb = b * 32768;
    // P1: lands {Ah0,Bh0}(t)
    SYNC(4);
    RD_B01();
    RD_A01();
    STG_A(nb, 0, t + 1);
    MFMA_Q(0, 0);
    // P2: lands Bh1(t)
    SYNC(4);
    RD_B23();
    STG_B(nb, 0, t + 1);
    MFMA_Q(0, 2);
    // P3: lands Ah1(t)
    SYNC(4);
    RD_A23();
    STG_B(nb, 1, t + 1);
    MFMA_Q(2, 0);
    // P4: no wait, no barrier
    STG_A(nb, 1, t + 1);
    MFMA_Q(2, 2);
  }
  {  // tail t = NT-1 (odd -> buf 1); entering queue = 8, no staging
    const int bb = 32768;
    SYNC(4);
    RD_B01();
    RD_A01();
    MFMA_Q(0, 0);
    SYNC(2);
    RD_B23();
    MFMA_Q(0, 2);
    SYNC(0);
    RD_A23();
    MFMA_Q(2, 0);
    MFMA_Q(2, 2);
  }

#undef STG_A
#undef STG_B
#undef LDA
#undef LDB
#undef SYNC
#undef MFMA_Q
#undef RD_B01
#undef RD_B23
#undef RD_A01
#undef RD_A23

  // epilogue: C/D layout col = lane&15, row = (lane>>4)*4 + reg (verified)
  const float sc = *scale_p;
  const int col_base = (tn << 7) + wn * 64;
  const int row_base = (tm << 7) + wm * 64 + lg * 4;
#pragma unroll
  for (int n = 0; n < 4; ++n) {
    const int col = col_base + n * 16 + lr;
    const float bv = bias[col];
#pragma unroll
    for (int m = 0; m < 4; ++m) {
      float* cp = C + (long)(row_base + m * 16) * N_DIM + col;
#pragma unroll
      for (int j = 0; j < 4; ++j)
        __builtin_nontemporal_store(acc[m][n][j] * sc + bv, cp + (long)j * N_DIM);
    }
  }
}

// ---------------- fallback (ws too small): reg-staged 128^2 kernel --------
__global__ __launch_bounds__(256, 2) void gemm_fb_kernel(
    const float* __restrict__ Af, const bf16_t* __restrict__ Bt,
    const float* __restrict__ scale_p, const float* __restrict__ bias,
    float* __restrict__ C) {
  __shared__ bf16_t lA[128][64];
  __shared__ bf16_t lB[128][64];
  const int nwg = gridDim.x;
  int wg = blockIdx.x;
  wg = (wg & 7) * (nwg >> 3) + (wg >> 3);
  const int tm = wg & 255;
  const int tn = wg >> 8;
  const int tid = threadIdx.x;
  const int wave = tid >> 6;
  const int lane = tid & 63;
  const int lr = lane & 15;
  const int lg = lane >> 4;
  const int wm = wave >> 1;
  const int wn = wave & 1;
  const long aRow0 = (long)tm * 128;
  const long bRow0 = (long)tn * 128;
  const bf16_t* bSrc = Bt + (bRow0 + (tid >> 3)) * K_DIM + (tid & 7) * 8;
  char* ldsB = (char*)&lB[0][0] + wave * 1024;
  f32x4 acc[4][4] = {};
  for (int k0 = 0; k0 < K_DIM; k0 += 64) {
    __syncthreads();
#pragma unroll
    for (int j = 0; j < 8; ++j) {
      const int e = j * 1024 + tid * 4;
      const int row = e >> 6;
      const int col = e & 63;
      float4 v = *(const float4*)(Af + (aRow0 + row) * K_DIM + k0 + col);
      bf16x4 o;
      o[0] = (__bf16)v.x; o[1] = (__bf16)v.y; o[2] = (__bf16)v.z; o[3] = (__bf16)v.w;
      *(bf16x4*)((char*)&lA[0][0] + (size_t)e * 2) = o;
    }
#pragma unroll
    for (int i = 0; i < 4; ++i)
      gload16(bSrc + (long)i * 32 * K_DIM + k0, ldsB + i * 4096);
    __syncthreads();
#pragma unroll
    for (int kk = 0; kk < 2; ++kk) {
      bf16x8 af[4], bg[4];
#pragma unroll
      for (int m = 0; m < 4; ++m)
        af[m] = *(const bf16x8*)&lA[wm * 64 + m * 16 + lr][kk * 32 + lg * 8];
#pragma unroll
      for (int n = 0; n < 4; ++n)
        bg[n] = *(const bf16x8*)&lB[wn * 64 + n * 16 + lr][kk * 32 + lg * 8];
#pragma unroll
      for (int m = 0; m < 4; ++m)
#pragma unroll
        for (int n = 0; n < 4; ++n)
          acc[m][n] = __builtin_amdgcn_mfma_f32_16x16x32_bf16(af[m], bg[n], acc[m][n], 0, 0, 0);
    }
  }
  const float s = *scale_p;
  const int col0 = (tn << 7) + wn * 64;
  const int row0 = (tm << 7) + wm * 64 + lg * 4;
#pragma unroll
  for (int n = 0; n < 4; ++n) {
    const int col = col0 + n * 16 + lr;
    const float bv = bias[col];
#pragma unroll
    for (int m = 0; m < 4; ++m) {
      float* cp = C + (long)(row0 + m * 16) * N_DIM + col;
#pragma unroll
      for (int j = 0; j < 4; ++j)
        cp[(long)j * N_DIM] = acc[m][n][j] * s + bv;
    }
  }
}

extern "C" void kernel_launch(void* const* d_in, const int* in_sizes, int n_in,
                              void* d_out, int out_size, void* d_ws, size_t ws_size,
                              hipStream_t stream) {
  const float* x = (const float*)d_in[0];
  const int* qw = (const int*)d_in[1];  // harness pushes ints as int32
  const float* scale = (const float*)d_in[2];
  const float* bias = (const float*)d_in[3];
  float* out = (float*)d_out;

  const size_t wt_bytes = (size_t)N_DIM * K_DIM * 2;  // 8 MB
  const size_t xb_bytes = (size_t)M_DIM * K_DIM * 2;  // 64 MB
  bf16_t* wt = (bf16_t*)d_ws;
  bf16_t* xb = (bf16_t*)((char*)d_ws + wt_bytes);
  const bool apre = ws_size >= wt_bytes + xb_bytes;

  cvt_w_kernel<<<dim3((K_DIM / 64) * (N_DIM / 64)), dim3(256), 0, stream>>>(qw, wt);

  if (apre) {
    cvt_x_kernel<<<dim3(2048), dim3(256), 0, stream>>>(x, xb);
    gemm128_kernel<<<dim3((M_DIM / 128) * (N_DIM / 128)), dim3(256), 0, stream>>>(
        xb, wt, scale, bias, out);
  } else {
    gemm_fb_kernel<<<dim3((M_DIM / 128) * (N_DIM / 128)), dim3(256), 0, stream>>>(
        x, wt, scale, bias, out);
  }
}